// Round 8
// baseline (165.870 us; speedup 1.0000x reference)
//
#include <hip/hip_runtime.h>

// Problem collapses: output = classifier(node 0) only.
//   out = dot(wc, mean(pool(lrelu(conv3(p2)+b3)))) + bc
//   p2  = pool(lrelu(conv2(12*P1) + 4*b2))   (node 1, indeg=4)
//   P1  = pool(lrelu(conv1(x)+b1))           (sum indegs over {0,2,4,6} = 12)
//
// R8: weights via LDS, not the scalar path. R7's s_load weights stalled on
// scalar-cache misses (72 s_loads/iter, 18KB tile > K$, all waves miss
// together -> VALUBusy 50%). Now: k0 repacks filters 9->12 floats (16B
// aligned); each block stages its weight tile to LDS once (coalesced
// float4), inner loop reads uniform-address ds_read_b128 (broadcast) into
// VGPRs -> v_fmac v,v,v. Weight tile aliases the combine buffer.

#define LRELU(v) fmaxf((v), 0.2f * (v))

#define P1H_ELEMS (32 * 32 * 34 * 36)
#define P2H_ELEMS (32 * 64 * 18 * 20)

// ---------- k0: repack w1/w2/w3 into 12-float padded, 16B-aligned ----------
__global__ __launch_bounds__(256) void k0(const float* __restrict__ w1,
                                          const float* __restrict__ w2,
                                          const float* __restrict__ w3,
                                          float* __restrict__ w1p,
                                          float* __restrict__ w2p,
                                          float* __restrict__ w3p) {
    int idx = blockIdx.x * 256 + threadIdx.x;   // (co,cin) pair id
    const float* s; float* d;
    if (idx < 128)            { s = w1 + idx * 9;          d = w1p + idx * 12; }
    else if (idx < 2176)      { s = w2 + (idx - 128) * 9;  d = w2p + (idx - 128) * 12; }
    else if (idx < 10368)     { s = w3 + (idx - 2176) * 9; d = w3p + (idx - 2176) * 12; }
    else return;
    #pragma unroll
    for (int i = 0; i < 9; ++i) d[i] = s[i];
    d[9] = 0.f; d[10] = 0.f; d[11] = 0.f;
}

// ---------- k1: conv1 4->32 @64x64, +b1, lrelu, pool2, *12 -> P1H ----------
__global__ __launch_bounds__(256, 4) void k1(const float* __restrict__ x,
                                             const float* __restrict__ w1p,
                                             const float* __restrict__ b1,
                                             float* __restrict__ P1H) {
    __shared__ __align__(16) float sw[4 * 4 * 12];   // [g][c][12]
    const int bx = blockIdx.x;          // 32 = rb(4) x cog(8)
    const int b  = blockIdx.y;
    const int rb = bx & 3, cog = bx >> 2;
    const int t  = threadIdx.x;
    const int l  = t & 63, wv = t >> 6;
    const int r  = l >> 4, q = l & 15;
    const int row0 = 16 * rb + 4 * wv + r;   // pre-pool row 0..63

    if (t < 48) *(float4*)&sw[t * 4] = *(const float4*)&w1p[cog * 192 + t * 4];

    // zero P1H halo cells owned by this block
    if (t >= 64 && t < 128) {
        int u = t - 64;
        int g = u >> 4, rr = (u >> 1) & 7, side = u & 1;
        P1H[((b * 32 + cog * 4 + g) * 34 + 8 * rb + 1 + rr) * 36 + (side ? 33 : 0)] = 0.f;
    } else if (t >= 128 && (rb == 0 || rb == 3)) {
        int u = t - 128;   // 0..127, need 144 -> handle 16 more below
        if (u < 144) {
            int g = u / 36, col = u % 36;
            P1H[((b * 32 + cog * 4 + g) * 34 + (rb ? 33 : 0)) * 36 + col] = 0.f;
        }
    }
    if (t < 16 && (rb == 0 || rb == 3)) {    // remaining 16 border cells
        int u = t + 128;
        int g = u / 36, col = u % 36;
        P1H[((b * 32 + cog * 4 + g) * 34 + (rb ? 33 : 0)) * 36 + col] = 0.f;
    }
    __syncthreads();

    const bool cL = (q > 0), cR = (q < 15);
    bool rv[3];
    #pragma unroll
    for (int d = 0; d < 3; ++d) rv[d] = (unsigned)(row0 - 1 + d) < 64u;

    float acc[4][4];
    #pragma unroll
    for (int g = 0; g < 4; ++g) {
        float bias = b1[cog * 4 + g];
        acc[g][0] = bias; acc[g][1] = bias; acc[g][2] = bias; acc[g][3] = bias;
    }

    #pragma unroll
    for (int c = 0; c < 4; ++c) {
        float win[3][6];
        #pragma unroll
        for (int d = 0; d < 3; ++d) {
            int base = ((b * 4 + c) * 64 + (row0 - 1 + d)) * 64;
            int iL = base + 4 * q - 2;
            int i4 = base + 4 * q;
            int iR = base + 4 * q + 4;
            iL = max(iL, 0); iL = min(iL, 32 * 4 * 64 * 64 - 2);
            i4 = max(i4, 0); i4 = min(i4, 32 * 4 * 64 * 64 - 4);
            iR = max(iR, 0); iR = min(iR, 32 * 4 * 64 * 64 - 2);
            float2 L = *(const float2*)(x + iL);
            float4 M = *(const float4*)(x + i4);
            float2 R = *(const float2*)(x + iR);
            win[d][0] = (rv[d] && cL) ? L.y : 0.f;
            win[d][1] = rv[d] ? M.x : 0.f;
            win[d][2] = rv[d] ? M.y : 0.f;
            win[d][3] = rv[d] ? M.z : 0.f;
            win[d][4] = rv[d] ? M.w : 0.f;
            win[d][5] = (rv[d] && cR) ? R.x : 0.f;
        }
        #pragma unroll
        for (int g = 0; g < 4; ++g) {
            const float* wg = &sw[(g * 4 + c) * 12];     // uniform -> ds broadcast
            float4 wa = *(const float4*)wg;
            float4 wb = *(const float4*)(wg + 4);
            float  w8 = wg[8];
            float wt[9] = {wa.x, wa.y, wa.z, wa.w, wb.x, wb.y, wb.z, wb.w, w8};
            #pragma unroll
            for (int d = 0; d < 3; ++d)
                #pragma unroll
                for (int j = 0; j < 3; ++j) {
                    float w = wt[3 * d + j];
                    acc[g][0] += w * win[d][j];
                    acc[g][1] += w * win[d][j + 1];
                    acc[g][2] += w * win[d][j + 2];
                    acc[g][3] += w * win[d][j + 3];
                }
        }
    }

    const int prow = 8 * rb + 2 * wv + (r >> 1);
    #pragma unroll
    for (int g = 0; g < 4; ++g) {
        float m0 = fmaxf(LRELU(acc[g][0]), LRELU(acc[g][1]));
        float m1 = fmaxf(LRELU(acc[g][2]), LRELU(acc[g][3]));
        float p0 = fmaxf(m0, __shfl_xor(m0, 16));   // all lanes execute
        float p1 = fmaxf(m1, __shfl_xor(m1, 16));
        if ((r & 1) == 0) {
            float* o = &P1H[((b * 32 + cog * 4 + g) * 34 + prow + 1) * 36 + 2 * q + 1];
            o[0] = 12.f * p0; o[1] = 12.f * p1;
        }
    }
}

// ---------- k2: conv2 32->64 @32x32, +4*b2, lrelu, pool2 -> p2H ------------
__global__ __launch_bounds__(256, 4) void k2(const float* __restrict__ P1H,
                                             const float* __restrict__ w2p,
                                             const float* __restrict__ b2,
                                             float* __restrict__ p2H) {
    __shared__ __align__(16) float smem[3 * 64 * 36];   // 27.6 KB; weights then cbuf
    const int bx  = blockIdx.x;           // 32 = cog(16) x rh(2)
    const int b   = blockIdx.y;
    const int cog = bx >> 1, rh = bx & 1;
    const int c0  = cog * 4;
    const int t   = threadIdx.x;
    const int l   = t & 63, wv = t >> 6;
    const int wvs = __builtin_amdgcn_readfirstlane(wv);
    const int R   = l >> 3, q = l & 7;
    const int r0  = 16 * rh + 2 * R;      // pre-pool rows r0, r0+1

    // stage weight tile: [g(4)][cin(32)][12] = 1536 floats
    #pragma unroll
    for (int i = t; i < 384; i += 256)
        *(float4*)&smem[i * 4] = *(const float4*)&w2p[cog * 1536 + i * 4];

    // zero p2H halo cells owned by this block
    if (t >= 128 && t < 192) {
        int u = t - 128;
        int g = u >> 4, rr = (u >> 1) & 7, side = u & 1;
        p2H[((b * 64 + c0 + g) * 18 + 8 * rh + 1 + rr) * 20 + (side ? 17 : 0)] = 0.f;
    } else if (t >= 192 && t < 256) {
        int u = t - 192;
        // 80 cells needed (4g x 20 cols); 64 threads do 0..63, then 16 redo
        int g = u / 20, col = u % 20;
        if (g < 4) p2H[((b * 64 + c0 + g) * 18 + (rh ? 17 : 0)) * 20 + col] = 0.f;
    }
    if (t < 16) {   // remaining 16 of the 80 border cells
        int u = t + 64;
        int g = u / 20, col = u % 20;
        p2H[((b * 64 + c0 + g) * 18 + (rh ? 17 : 0)) * 20 + col] = 0.f;
    }
    __syncthreads();

    float acc[4][2][4];
    #pragma unroll
    for (int g = 0; g < 4; ++g) {
        float bias = (wvs == 0) ? 4.f * b2[c0 + g] : 0.f;
        #pragma unroll
        for (int orow = 0; orow < 2; ++orow) {
            acc[g][orow][0] = bias; acc[g][orow][1] = bias;
            acc[g][orow][2] = bias; acc[g][orow][3] = bias;
        }
    }

    #pragma unroll 4
    for (int cl = 0; cl < 8; ++cl) {
        const int cin = wvs * 8 + cl;
        const int plane = (b * 32 + cin) * 34;
        float win[4][6];
        #pragma unroll
        for (int d = 0; d < 4; ++d) {
            const float* pr = &P1H[(plane + r0 + d) * 36 + 4 * q];
            float4 M  = *(const float4*)pr;
            float2 Rt = *(const float2*)(pr + 4);
            win[d][0] = M.x; win[d][1] = M.y; win[d][2] = M.z;
            win[d][3] = M.w; win[d][4] = Rt.x; win[d][5] = Rt.y;
        }
        #pragma unroll
        for (int g = 0; g < 4; ++g) {
            const float* wg = &smem[(g * 32 + cin) * 12];   // uniform ds_read
            float4 wa = *(const float4*)wg;
            float4 wb = *(const float4*)(wg + 4);
            float  w8 = wg[8];
            float wt[9] = {wa.x, wa.y, wa.z, wa.w, wb.x, wb.y, wb.z, wb.w, w8};
            #pragma unroll
            for (int d = 0; d < 3; ++d)
                #pragma unroll
                for (int j = 0; j < 3; ++j) {
                    float w = wt[3 * d + j];
                    #pragma unroll
                    for (int k = 0; k < 4; ++k) {
                        acc[g][0][k] += w * win[d][j + k];
                        acc[g][1][k] += w * win[d + 1][j + k];
                    }
                }
        }
    }

    __syncthreads();   // weights dead; smem becomes combine buffer
    if (wvs > 0) {
        float* cb = &smem[((wvs - 1) * 64 + l) * 36];
        #pragma unroll
        for (int g = 0; g < 4; ++g)
            #pragma unroll
            for (int orow = 0; orow < 2; ++orow)
                *(float4*)&cb[(g * 2 + orow) * 4] =
                    make_float4(acc[g][orow][0], acc[g][orow][1],
                                acc[g][orow][2], acc[g][orow][3]);
    }
    __syncthreads();

    if (wvs == 0) {
        #pragma unroll
        for (int k = 0; k < 3; ++k) {
            const float* cb = &smem[(k * 64 + l) * 36];
            #pragma unroll
            for (int g = 0; g < 4; ++g)
                #pragma unroll
                for (int orow = 0; orow < 2; ++orow) {
                    float4 v = *(const float4*)&cb[(g * 2 + orow) * 4];
                    acc[g][orow][0] += v.x; acc[g][orow][1] += v.y;
                    acc[g][orow][2] += v.z; acc[g][orow][3] += v.w;
                }
        }
        #pragma unroll
        for (int g = 0; g < 4; ++g) {
            float p0 = fmaxf(fmaxf(LRELU(acc[g][0][0]), LRELU(acc[g][0][1])),
                             fmaxf(LRELU(acc[g][1][0]), LRELU(acc[g][1][1])));
            float p1 = fmaxf(fmaxf(LRELU(acc[g][0][2]), LRELU(acc[g][0][3])),
                             fmaxf(LRELU(acc[g][1][2]), LRELU(acc[g][1][3])));
            float* o = &p2H[((b * 64 + c0 + g) * 18 + (8 * rh + R) + 1) * 20 + 2 * q + 1];
            o[0] = p0; o[1] = p1;
        }
    }
}

// ---------- k3: conv3 64->128 @16x16, +b3, lrelu, pool2, mean, dot ---------
__global__ __launch_bounds__(256, 2) void k3(const float* __restrict__ p2H,
                                             const float* __restrict__ w3p,
                                             const float* __restrict__ b3,
                                             const float* __restrict__ wc,
                                             const float* __restrict__ bc,
                                             float* __restrict__ out) {
    __shared__ __align__(16) float smem[3 * 64 * 36];   // 27.6 KB; weights then cbuf
    const int cog = blockIdx.x;           // 0..15 -> 8 co
    const int b   = blockIdx.y;
    const int t   = threadIdx.x;
    const int l   = t & 63, wv = t >> 6;
    const int wvs = __builtin_amdgcn_readfirstlane(wv);
    const int r   = l >> 2, q = l & 3;

    // stage weight tile: [g(8)][cin(64)][12] = 6144 floats
    #pragma unroll
    for (int i = t; i < 1536; i += 256)
        *(float4*)&smem[i * 4] = *(const float4*)&w3p[cog * 6144 + i * 4];
    __syncthreads();

    float acc[8][4];
    #pragma unroll
    for (int g = 0; g < 8; ++g) {
        float bias = (wvs == 0) ? b3[cog * 8 + g] : 0.f;
        acc[g][0] = bias; acc[g][1] = bias; acc[g][2] = bias; acc[g][3] = bias;
    }

    #pragma unroll 4
    for (int cl = 0; cl < 16; ++cl) {
        const int cin = wvs * 16 + cl;
        const int plane = (b * 64 + cin) * 18;
        float win[3][6];
        #pragma unroll
        for (int d = 0; d < 3; ++d) {
            const float* pr = &p2H[(plane + r + d) * 20 + 4 * q];
            float4 M  = *(const float4*)pr;
            float2 Rt = *(const float2*)(pr + 4);
            win[d][0] = M.x; win[d][1] = M.y; win[d][2] = M.z;
            win[d][3] = M.w; win[d][4] = Rt.x; win[d][5] = Rt.y;
        }
        #pragma unroll
        for (int g = 0; g < 8; ++g) {
            const float* wg = &smem[(g * 64 + cin) * 12];   // uniform ds_read
            float4 wa = *(const float4*)wg;
            float4 wb = *(const float4*)(wg + 4);
            float  w8 = wg[8];
            float wt[9] = {wa.x, wa.y, wa.z, wa.w, wb.x, wb.y, wb.z, wb.w, w8};
            #pragma unroll
            for (int d = 0; d < 3; ++d)
                #pragma unroll
                for (int j = 0; j < 3; ++j) {
                    float w = wt[3 * d + j];
                    acc[g][0] += w * win[d][j];
                    acc[g][1] += w * win[d][j + 1];
                    acc[g][2] += w * win[d][j + 2];
                    acc[g][3] += w * win[d][j + 3];
                }
        }
    }

    __syncthreads();   // weights dead; smem becomes combine buffer
    if (wvs > 0) {
        float* cb = &smem[((wvs - 1) * 64 + l) * 36];
        #pragma unroll
        for (int g = 0; g < 8; ++g)
            *(float4*)&cb[g * 4] =
                make_float4(acc[g][0], acc[g][1], acc[g][2], acc[g][3]);
    }
    __syncthreads();

    if (wvs == 0) {
        #pragma unroll
        for (int k = 0; k < 3; ++k) {
            const float* cb = &smem[(k * 64 + l) * 36];
            #pragma unroll
            for (int g = 0; g < 8; ++g) {
                float4 v = *(const float4*)&cb[g * 4];
                acc[g][0] += v.x; acc[g][1] += v.y;
                acc[g][2] += v.z; acc[g][3] += v.w;
            }
        }
        float vsum = 0.f;
        #pragma unroll
        for (int g = 0; g < 8; ++g) {
            float m0 = fmaxf(LRELU(acc[g][0]), LRELU(acc[g][1]));
            float m1 = fmaxf(LRELU(acc[g][2]), LRELU(acc[g][3]));
            float pm0 = fmaxf(m0, __shfl_xor(m0, 4));   // pool rows r, r+1
            float pm1 = fmaxf(m1, __shfl_xor(m1, 4));
            float contrib = ((r & 1) == 0) ? (pm0 + pm1) : 0.f;
            vsum += contrib * wc[cog * 8 + g];
        }
        #pragma unroll
        for (int off = 32; off > 0; off >>= 1) vsum += __shfl_xor(vsum, off);
        if (l == 0) {
            float o = vsum * (1.f / 64.f);
            if (cog == 0) o += bc[0];
            atomicAdd(&out[b], o);
        }
    }
}

extern "C" void kernel_launch(void* const* d_in, const int* in_sizes, int n_in,
                              void* d_out, int out_size, void* d_ws, size_t ws_size,
                              hipStream_t stream) {
    const float* x  = (const float*)d_in[0];
    const float* w1 = (const float*)d_in[1];
    const float* b1 = (const float*)d_in[2];
    const float* w2 = (const float*)d_in[3];
    const float* b2 = (const float*)d_in[4];
    const float* w3 = (const float*)d_in[5];
    const float* b3 = (const float*)d_in[6];
    const float* wc = (const float*)d_in[7];
    const float* bc = (const float*)d_in[8];
    float* out = (float*)d_out;

    float* P1H = (float*)d_ws;                    // [32][32][34][36] ~5.0 MB
    float* p2H = P1H + P1H_ELEMS;                 // [32][64][18][20] ~1.8 MB
    float* w1p = p2H + P2H_ELEMS;                 // 32*4*12
    float* w2p = w1p + 32 * 4 * 12;               // 64*32*12
    float* w3p = w2p + 64 * 32 * 12;              // 128*64*12

    hipMemsetAsync(out, 0, 32 * sizeof(float), stream);
    k0<<<41, 256, 0, stream>>>(w1, w2, w3, w1p, w2p, w3p);
    k1<<<dim3(32, 32), 256, 0, stream>>>(x, w1p, b1, P1H);
    k2<<<dim3(32, 32), 256, 0, stream>>>(P1H, w2p, b2, p2H);
    k3<<<dim3(16, 32), 256, 0, stream>>>(p2H, w3p, b3, wc, bc, out);
}

// Round 10
// 162.247 us; speedup vs baseline: 1.0223x; 1.0223x over previous
//
#include <hip/hip_runtime.h>

// Problem collapses: output = classifier(node 0) only.
//   out = dot(wc, mean(pool(lrelu(conv3(p2)+b3)))) + bc
//   p2  = pool(lrelu(conv2(12*P1) + 4*b2))   (node 1, indeg=4)
//   P1  = pool(lrelu(conv1(x)+b1))           (sum indegs over {0,2,4,6} = 12)
//
// R10 = R9 + fix: k2 combine-buffer stride back to 36 floats (R9 used 16
// but k2 threads store 32 floats of partials -> lane overlap, absmax 18).
// Weights staged to LDS per block from the packed array (pad 9->12 in the
// LDS-store mapping), read via ds immediate offsets (broadcast). Window
// loads saddr-form. Latency hidden by TLP (1024 blocks, 4 blocks/CU).

#define LRELU(v) fmaxf((v), 0.2f * (v))

#define P1H_ELEMS (32 * 32 * 34 * 36)
#define P2H_ELEMS (32 * 64 * 18 * 20)

// ---------- k1: conv1 4->32 @64x64, +b1, lrelu, pool2, *12 -> P1H ----------
__global__ __launch_bounds__(256, 4) void k1(const float* __restrict__ x,
                                             const float* __restrict__ w1,
                                             const float* __restrict__ b1,
                                             float* __restrict__ P1H) {
    const int bx = blockIdx.x;          // 32 = rb(4) x cog(8)
    const int b  = blockIdx.y;
    const int rb = bx & 3, cog = bx >> 2;
    const int t  = threadIdx.x;
    const int l  = t & 63, wv = t >> 6;
    const int r  = l >> 4, q = l & 15;
    const int row0 = 16 * rb + 4 * wv + r;   // pre-pool row 0..63

    // zero P1H halo cells owned by this block
    if (t < 64) {
        int g = t >> 4, rr = (t >> 1) & 7, side = t & 1;
        P1H[((b * 32 + cog * 4 + g) * 34 + 8 * rb + 1 + rr) * 36 + (side ? 33 : 0)] = 0.f;
    } else if (t < 208 && (rb == 0 || rb == 3)) {
        int u = t - 64;
        int g = u / 36, col = u % 36;
        P1H[((b * 32 + cog * 4 + g) * 34 + (rb ? 33 : 0)) * 36 + col] = 0.f;
    }

    const bool cL = (q > 0), cR = (q < 15);
    bool rv[3];
    #pragma unroll
    for (int d = 0; d < 3; ++d) rv[d] = (unsigned)(row0 - 1 + d) < 64u;

    float acc[4][4];
    #pragma unroll
    for (int g = 0; g < 4; ++g) {
        float bias = b1[cog * 4 + g];
        acc[g][0] = bias; acc[g][1] = bias; acc[g][2] = bias; acc[g][3] = bias;
    }

    #pragma unroll
    for (int c = 0; c < 4; ++c) {
        float win[3][6];
        #pragma unroll
        for (int d = 0; d < 3; ++d) {
            int base = ((b * 4 + c) * 64 + (row0 - 1 + d)) * 64;
            int iL = base + 4 * q - 2;
            int i4 = base + 4 * q;
            int iR = base + 4 * q + 4;
            iL = max(iL, 0); iL = min(iL, 32 * 4 * 64 * 64 - 2);
            i4 = max(i4, 0); i4 = min(i4, 32 * 4 * 64 * 64 - 4);
            iR = max(iR, 0); iR = min(iR, 32 * 4 * 64 * 64 - 2);
            float2 L = *(const float2*)(x + iL);
            float4 M = *(const float4*)(x + i4);
            float2 R = *(const float2*)(x + iR);
            win[d][0] = (rv[d] && cL) ? L.y : 0.f;
            win[d][1] = rv[d] ? M.x : 0.f;
            win[d][2] = rv[d] ? M.y : 0.f;
            win[d][3] = rv[d] ? M.z : 0.f;
            win[d][4] = rv[d] ? M.w : 0.f;
            win[d][5] = (rv[d] && cR) ? R.x : 0.f;
        }
        #pragma unroll
        for (int g = 0; g < 4; ++g) {
            const float* wp = &w1[((cog * 4 + g) * 4 + c) * 9];  // scalar, tiny K$ set
            #pragma unroll
            for (int d = 0; d < 3; ++d)
                #pragma unroll
                for (int j = 0; j < 3; ++j) {
                    float w = wp[3 * d + j];
                    acc[g][0] += w * win[d][j];
                    acc[g][1] += w * win[d][j + 1];
                    acc[g][2] += w * win[d][j + 2];
                    acc[g][3] += w * win[d][j + 3];
                }
        }
    }

    const int prow = 8 * rb + 2 * wv + (r >> 1);
    #pragma unroll
    for (int g = 0; g < 4; ++g) {
        float m0 = fmaxf(LRELU(acc[g][0]), LRELU(acc[g][1]));
        float m1 = fmaxf(LRELU(acc[g][2]), LRELU(acc[g][3]));
        float p0 = fmaxf(m0, __shfl_xor(m0, 16));   // all lanes execute
        float p1 = fmaxf(m1, __shfl_xor(m1, 16));
        if ((r & 1) == 0) {
            float* o = &P1H[((b * 32 + cog * 4 + g) * 34 + prow + 1) * 36 + 2 * q + 1];
            o[0] = 12.f * p0; o[1] = 12.f * p1;
        }
    }
}

// ---------- k2: conv2 32->64 @32x32, +4*b2, lrelu, pool2 -> p2H ------------
// block = (4-co group x row-half); waves split cin (8 each); LDS weights.
__global__ __launch_bounds__(256, 4) void k2(const float* __restrict__ P1H,
                                             const float* __restrict__ w2,
                                             const float* __restrict__ b2,
                                             float* __restrict__ p2H) {
    __shared__ __align__(16) float smem[6912];   // 27.6 KB: weights [4][32][12]; cbuf stride 36
    const int bx  = blockIdx.x;           // 32 = cog(16) x rh(2)
    const int b   = blockIdx.y;
    const int cog = bx >> 1, rh = bx & 1;
    const int c0  = cog * 4;
    const int t   = threadIdx.x;
    const int l   = t & 63;
    const int wvs = __builtin_amdgcn_readfirstlane(t >> 6);
    const int R   = l >> 3, q = l & 7;
    const int r0  = 16 * rh + 2 * R;      // pre-pool rows r0, r0+1

    // stage weights: packed 9 -> LDS stride 12 (coalesced dword reads)
    for (int i = t; i < 1152; i += 256) {
        int f = i / 9, j = i - f * 9;
        smem[f * 12 + j] = w2[cog * 1152 + i];
    }
    // zero p2H halo cells owned by this block
    if (t >= 128 && t < 192) {
        int u = t - 128;
        int g = u >> 4, rr = (u >> 1) & 7, side = u & 1;
        p2H[((b * 64 + c0 + g) * 18 + 8 * rh + 1 + rr) * 20 + (side ? 17 : 0)] = 0.f;
    } else if (t >= 192) {
        int u = t - 192;
        int g = u / 20, col = u % 20;
        if (g < 4) p2H[((b * 64 + c0 + g) * 18 + (rh ? 17 : 0)) * 20 + col] = 0.f;
    }
    if (t < 16) {   // remaining 16 of the 80 border-row cells
        int u = t + 64;
        int g = u / 20, col = u % 20;
        p2H[((b * 64 + c0 + g) * 18 + (rh ? 17 : 0)) * 20 + col] = 0.f;
    }
    __syncthreads();

    float acc[4][2][4];
    #pragma unroll
    for (int g = 0; g < 4; ++g) {
        float bias = (wvs == 0) ? 4.f * b2[c0 + g] : 0.f;
        #pragma unroll
        for (int orow = 0; orow < 2; ++orow) {
            acc[g][orow][0] = bias; acc[g][orow][1] = bias;
            acc[g][orow][2] = bias; acc[g][orow][3] = bias;
        }
    }

    #pragma unroll
    for (int cl = 0; cl < 8; ++cl) {
        const int cin = wvs * 8 + cl;
        const float* pb = P1H + (((b * 32 + cin) * 34 + r0) * 36 + 4 * q);
        float win[4][6];
        #pragma unroll
        for (int d = 0; d < 4; ++d) {
            float4 M  = *(const float4*)(pb + d * 36);
            float2 Rt = *(const float2*)(pb + d * 36 + 4);
            win[d][0] = M.x; win[d][1] = M.y; win[d][2] = M.z;
            win[d][3] = M.w; win[d][4] = Rt.x; win[d][5] = Rt.y;
        }
        #pragma unroll
        for (int g = 0; g < 4; ++g) {
            const float* wg = &smem[(g * 32 + cin) * 12];   // ds imm offsets
            float4 wa = *(const float4*)wg;
            float4 wb = *(const float4*)(wg + 4);
            float  w8 = wg[8];
            float wt[9] = {wa.x, wa.y, wa.z, wa.w, wb.x, wb.y, wb.z, wb.w, w8};
            #pragma unroll
            for (int d = 0; d < 3; ++d)
                #pragma unroll
                for (int j = 0; j < 3; ++j) {
                    float w = wt[3 * d + j];
                    #pragma unroll
                    for (int k = 0; k < 4; ++k) {
                        acc[g][0][k] += w * win[d][j + k];
                        acc[g][1][k] += w * win[d + 1][j + k];
                    }
                }
        }
    }

    __syncthreads();   // weights dead; smem becomes combine buffer (stride 36)
    if (wvs > 0) {
        float* cb = &smem[((wvs - 1) * 64 + l) * 36];
        #pragma unroll
        for (int g = 0; g < 4; ++g)
            #pragma unroll
            for (int orow = 0; orow < 2; ++orow)
                *(float4*)&cb[(g * 2 + orow) * 4] =
                    make_float4(acc[g][orow][0], acc[g][orow][1],
                                acc[g][orow][2], acc[g][orow][3]);
    }
    __syncthreads();

    if (wvs == 0) {
        #pragma unroll
        for (int k = 0; k < 3; ++k) {
            const float* cb = &smem[(k * 64 + l) * 36];
            #pragma unroll
            for (int g = 0; g < 4; ++g)
                #pragma unroll
                for (int orow = 0; orow < 2; ++orow) {
                    float4 v = *(const float4*)&cb[(g * 2 + orow) * 4];
                    acc[g][orow][0] += v.x; acc[g][orow][1] += v.y;
                    acc[g][orow][2] += v.z; acc[g][orow][3] += v.w;
                }
        }
        #pragma unroll
        for (int g = 0; g < 4; ++g) {
            float p0 = fmaxf(fmaxf(LRELU(acc[g][0][0]), LRELU(acc[g][0][1])),
                             fmaxf(LRELU(acc[g][1][0]), LRELU(acc[g][1][1])));
            float p1 = fmaxf(fmaxf(LRELU(acc[g][0][2]), LRELU(acc[g][0][3])),
                             fmaxf(LRELU(acc[g][1][2]), LRELU(acc[g][1][3])));
            float* o = &p2H[((b * 64 + c0 + g) * 18 + (8 * rh + R) + 1) * 20 + 2 * q + 1];
            o[0] = p0; o[1] = p1;
        }
    }
}

// ---------- k3: conv3 64->128 @16x16, +b3, lrelu, pool2, mean, dot ---------
// block = 4-co group (32 of them); waves split cin (16 each); LDS weights.
__global__ __launch_bounds__(256, 4) void k3(const float* __restrict__ p2H,
                                             const float* __restrict__ w3,
                                             const float* __restrict__ b3,
                                             const float* __restrict__ wc,
                                             const float* __restrict__ bc,
                                             float* __restrict__ out) {
    __shared__ __align__(16) float smem[3072];   // 12 KB: weights [4][64][12]; cbuf stride 16
    const int cog = blockIdx.x;           // 0..31 -> 4 co
    const int b   = blockIdx.y;
    const int c0  = cog * 4;
    const int t   = threadIdx.x;
    const int l   = t & 63;
    const int wvs = __builtin_amdgcn_readfirstlane(t >> 6);
    const int r   = l >> 2, q = l & 3;

    // stage weights: packed 9 -> LDS stride 12 (2304 dwords, coalesced)
    for (int i = t; i < 2304; i += 256) {
        int f = i / 9, j = i - f * 9;
        smem[f * 12 + j] = w3[cog * 2304 + i];
    }
    __syncthreads();

    float acc[4][4];
    #pragma unroll
    for (int g = 0; g < 4; ++g) {
        float bias = (wvs == 0) ? b3[c0 + g] : 0.f;
        acc[g][0] = bias; acc[g][1] = bias; acc[g][2] = bias; acc[g][3] = bias;
    }

    #pragma unroll
    for (int cl = 0; cl < 16; ++cl) {
        const int cin = wvs * 16 + cl;
        const float* pb = p2H + (((b * 64 + cin) * 18 + r) * 20 + 4 * q);
        float win[3][6];
        #pragma unroll
        for (int d = 0; d < 3; ++d) {
            float4 M  = *(const float4*)(pb + d * 20);
            float2 Rt = *(const float2*)(pb + d * 20 + 4);
            win[d][0] = M.x; win[d][1] = M.y; win[d][2] = M.z;
            win[d][3] = M.w; win[d][4] = Rt.x; win[d][5] = Rt.y;
        }
        #pragma unroll
        for (int g = 0; g < 4; ++g) {
            const float* wg = &smem[(g * 64 + cin) * 12];   // ds imm offsets
            float4 wa = *(const float4*)wg;
            float4 wb = *(const float4*)(wg + 4);
            float  w8 = wg[8];
            float wt[9] = {wa.x, wa.y, wa.z, wa.w, wb.x, wb.y, wb.z, wb.w, w8};
            #pragma unroll
            for (int d = 0; d < 3; ++d)
                #pragma unroll
                for (int j = 0; j < 3; ++j) {
                    float w = wt[3 * d + j];
                    acc[g][0] += w * win[d][j];
                    acc[g][1] += w * win[d][j + 1];
                    acc[g][2] += w * win[d][j + 2];
                    acc[g][3] += w * win[d][j + 3];
                }
        }
    }

    __syncthreads();   // weights dead; smem becomes combine buffer (stride 16)
    if (wvs > 0) {
        float* cb = &smem[((wvs - 1) * 64 + l) * 16];
        #pragma unroll
        for (int g = 0; g < 4; ++g)
            *(float4*)&cb[g * 4] =
                make_float4(acc[g][0], acc[g][1], acc[g][2], acc[g][3]);
    }
    __syncthreads();

    if (wvs == 0) {
        #pragma unroll
        for (int k = 0; k < 3; ++k) {
            const float* cb = &smem[(k * 64 + l) * 16];
            #pragma unroll
            for (int g = 0; g < 4; ++g) {
                float4 v = *(const float4*)&cb[g * 4];
                acc[g][0] += v.x; acc[g][1] += v.y;
                acc[g][2] += v.z; acc[g][3] += v.w;
            }
        }
        float vsum = 0.f;
        #pragma unroll
        for (int g = 0; g < 4; ++g) {
            float m0 = fmaxf(LRELU(acc[g][0]), LRELU(acc[g][1]));
            float m1 = fmaxf(LRELU(acc[g][2]), LRELU(acc[g][3]));
            float pm0 = fmaxf(m0, __shfl_xor(m0, 4));   // pool rows r, r+1
            float pm1 = fmaxf(m1, __shfl_xor(m1, 4));
            float contrib = ((r & 1) == 0) ? (pm0 + pm1) : 0.f;
            vsum += contrib * wc[c0 + g];
        }
        #pragma unroll
        for (int off = 32; off > 0; off >>= 1) vsum += __shfl_xor(vsum, off);
        if (l == 0) {
            float o = vsum * (1.f / 64.f);
            if (cog == 0) o += bc[0];
            atomicAdd(&out[b], o);
        }
    }
}

extern "C" void kernel_launch(void* const* d_in, const int* in_sizes, int n_in,
                              void* d_out, int out_size, void* d_ws, size_t ws_size,
                              hipStream_t stream) {
    const float* x  = (const float*)d_in[0];
    const float* w1 = (const float*)d_in[1];
    const float* b1 = (const float*)d_in[2];
    const float* w2 = (const float*)d_in[3];
    const float* b2 = (const float*)d_in[4];
    const float* w3 = (const float*)d_in[5];
    const float* b3 = (const float*)d_in[6];
    const float* wc = (const float*)d_in[7];
    const float* bc = (const float*)d_in[8];
    float* out = (float*)d_out;

    float* P1H = (float*)d_ws;                    // [32][32][34][36] ~5.0 MB
    float* p2H = P1H + P1H_ELEMS;                 // [32][64][18][20] ~1.8 MB

    hipMemsetAsync(out, 0, 32 * sizeof(float), stream);
    k1<<<dim3(32, 32), 256, 0, stream>>>(x, w1, b1, P1H);
    k2<<<dim3(32, 32), 256, 0, stream>>>(P1H, w2, b2, p2H);
    k3<<<dim3(32, 32), 256, 0, stream>>>(p2H, w3, b3, wc, bc, out);
}

// Round 11
// 140.387 us; speedup vs baseline: 1.1815x; 1.1557x over previous
//
#include <hip/hip_runtime.h>

// Problem collapses: output = classifier(node 0) only.
//   out = dot(wc, mean(pool(lrelu(conv3(p2)+b3)))) + bc
//   p2  = pool(lrelu(conv2(12*P1) + 4*b2))   (node 1, indeg=4)
//   P1  = pool(lrelu(conv1(x)+b1))           (sum indegs over {0,2,4,6} = 12)
//
// R11: traffic attack. k2 was memory-bound (FETCH 48MB = P1H re-read ~10x,
// WRITE 72MB = partial-line RMW). Now: (1) k2 waves split CO (32 co/block),
// input staged to LDS in 8-cin chunks -> P1H read ~3x total; (2) all global
// stores are full-line float4 rows assembled in LDS incl. halo zeros (no
// RMW, no scattered halo writes); (3) k3 at 8 co/block halves p2H re-reads.

#define LRELU(v) fmaxf((v), 0.2f * (v))

#define P1H_ELEMS (32 * 32 * 34 * 36)
#define P2H_ELEMS (32 * 64 * 18 * 20)

// ---------- k1: conv1 4->32 @64x64, +b1, lrelu, pool2, *12 -> P1H ----------
__global__ __launch_bounds__(256, 4) void k1(const float* __restrict__ x,
                                             const float* __restrict__ w1,
                                             const float* __restrict__ b1,
                                             float* __restrict__ P1H) {
    __shared__ __align__(16) float obuf[1152];     // [4co][8prow][36]
    const int bx = blockIdx.x;                     // 32 = rb(4) x cog(8)
    const int b  = blockIdx.y;
    const int rb = bx & 3, cog = bx >> 2;
    const int t  = threadIdx.x;
    const int l  = t & 63, wv = t >> 6;
    const int r  = l >> 4, q = l & 15;
    const int row0 = 16 * rb + 4 * wv + r;         // pre-pool row 0..63

    for (int i = t; i < 288; i += 256)
        *(float4*)&obuf[4 * i] = make_float4(0.f, 0.f, 0.f, 0.f);
    __syncthreads();

    const bool cL = (q > 0), cR = (q < 15);
    bool rv[3];
    #pragma unroll
    for (int d = 0; d < 3; ++d) rv[d] = (unsigned)(row0 - 1 + d) < 64u;

    float acc[4][4];
    #pragma unroll
    for (int g = 0; g < 4; ++g) {
        float bias = b1[cog * 4 + g];
        acc[g][0] = bias; acc[g][1] = bias; acc[g][2] = bias; acc[g][3] = bias;
    }

    #pragma unroll
    for (int c = 0; c < 4; ++c) {
        float win[3][6];
        #pragma unroll
        for (int d = 0; d < 3; ++d) {
            int base = ((b * 4 + c) * 64 + (row0 - 1 + d)) * 64;
            int iL = base + 4 * q - 2;
            int i4 = base + 4 * q;
            int iR = base + 4 * q + 4;
            iL = max(iL, 0); iL = min(iL, 32 * 4 * 64 * 64 - 2);
            i4 = max(i4, 0); i4 = min(i4, 32 * 4 * 64 * 64 - 4);
            iR = max(iR, 0); iR = min(iR, 32 * 4 * 64 * 64 - 2);
            float2 L  = *(const float2*)(x + iL);
            float4 M  = *(const float4*)(x + i4);
            float2 R2 = *(const float2*)(x + iR);
            win[d][0] = (rv[d] && cL) ? L.y : 0.f;
            win[d][1] = rv[d] ? M.x : 0.f;
            win[d][2] = rv[d] ? M.y : 0.f;
            win[d][3] = rv[d] ? M.z : 0.f;
            win[d][4] = rv[d] ? M.w : 0.f;
            win[d][5] = (rv[d] && cR) ? R2.x : 0.f;
        }
        #pragma unroll
        for (int g = 0; g < 4; ++g) {
            const float* wp = &w1[((cog * 4 + g) * 4 + c) * 9];  // scalar K$ set (tiny)
            #pragma unroll
            for (int d = 0; d < 3; ++d)
                #pragma unroll
                for (int j = 0; j < 3; ++j) {
                    float w = wp[3 * d + j];
                    acc[g][0] += w * win[d][j];
                    acc[g][1] += w * win[d][j + 1];
                    acc[g][2] += w * win[d][j + 2];
                    acc[g][3] += w * win[d][j + 3];
                }
        }
    }

    const int prow_l = 2 * wv + (r >> 1);
    #pragma unroll
    for (int g = 0; g < 4; ++g) {
        float m0 = fmaxf(LRELU(acc[g][0]), LRELU(acc[g][1]));
        float m1 = fmaxf(LRELU(acc[g][2]), LRELU(acc[g][3]));
        float p0 = fmaxf(m0, __shfl_xor(m0, 16));   // all lanes execute
        float p1 = fmaxf(m1, __shfl_xor(m1, 16));
        if ((r & 1) == 0) {
            obuf[(g * 8 + prow_l) * 36 + 2 * q + 1] = 12.f * p0;
            obuf[(g * 8 + prow_l) * 36 + 2 * q + 2] = 12.f * p1;
        }
    }
    __syncthreads();

    // full-line coalesced stores (rows incl. halo cols)
    for (int i = t; i < 288; i += 256) {
        int co_l = i / 72, rem = i % 72, pr = rem / 9, cw = rem % 9;
        *(float4*)&P1H[((b * 32 + cog * 4 + co_l) * 34 + 8 * rb + pr + 1) * 36 + 4 * cw] =
            *(const float4*)&obuf[4 * i];
    }
    if (rb == 0 || rb == 3) {
        int h = rb ? 33 : 0;
        for (int i = t; i < 36; i += 256) {
            int co_l = i / 9, cw = i % 9;
            *(float4*)&P1H[((b * 32 + cog * 4 + co_l) * 34 + h) * 36 + 4 * cw] =
                make_float4(0.f, 0.f, 0.f, 0.f);
        }
    }
}

// ---------- k2: conv2 32->64 @32x32, +4*b2, lrelu, pool2 -> p2H ------------
// Waves split CO (8 each, 32/block); block = 4-row strip; LDS input chunks.
__global__ __launch_bounds__(256, 2) void k2(const float* __restrict__ P1H,
                                             const float* __restrict__ w2,
                                             const float* __restrict__ b2,
                                             float* __restrict__ p2H) {
    __shared__ __align__(16) float wtile[12288];   // [32co][32cin][12]  49.2 KB
    __shared__ __align__(16) float xin[1728];      // [8cin][6row][36]    6.9 KB
    __shared__ __align__(16) float obuf[1280];     // [32co][2prow][20]   5.1 KB
    const int bx = blockIdx.x;                     // 16 = cog(2) x rs(8)
    const int b  = blockIdx.y;
    const int cog = bx >> 3, rs = bx & 7;
    const int t  = threadIdx.x, l = t & 63;
    const int wvs = __builtin_amdgcn_readfirstlane(t >> 6);
    const int q  = l & 15, R = l >> 4;             // cols 2q,2q+1; row rs*4+R

    // stage weights: contiguous float4 reads, scatter to stride-12 (pad 9->12)
    for (int i = t; i < 2304; i += 256) {
        float4 v = *(const float4*)&w2[cog * 9216 + 4 * i];
        int e = 4 * i;
        wtile[((e + 0) / 9) * 12 + (e + 0) % 9] = v.x;
        wtile[((e + 1) / 9) * 12 + (e + 1) % 9] = v.y;
        wtile[((e + 2) / 9) * 12 + (e + 2) % 9] = v.z;
        wtile[((e + 3) / 9) * 12 + (e + 3) % 9] = v.w;
    }
    for (int i = t; i < 320; i += 256)
        *(float4*)&obuf[4 * i] = make_float4(0.f, 0.f, 0.f, 0.f);

    float acc[8][2];
    #pragma unroll
    for (int g = 0; g < 8; ++g) {
        float bias = 4.f * b2[cog * 32 + wvs * 8 + g];
        acc[g][0] = bias; acc[g][1] = bias;
    }

    for (int cc = 0; cc < 4; ++cc) {
        __syncthreads();
        for (int i = t; i < 432; i += 256) {       // 8 cin x 6 rows x 9 f4
            int cin_l = i / 54, rem = i % 54;
            *(float4*)&xin[cin_l * 216 + 4 * rem] =
                *(const float4*)&P1H[((b * 32 + cc * 8 + cin_l) * 34 + rs * 4) * 36 + 4 * rem];
        }
        __syncthreads();
        #pragma unroll
        for (int cl = 0; cl < 8; ++cl) {
            float win[3][4];
            #pragma unroll
            for (int d = 0; d < 3; ++d) {
                const float* xr = &xin[cl * 216 + (R + d) * 36 + 2 * q];
                float2 a = *(const float2*)xr;
                float2 c = *(const float2*)(xr + 2);
                win[d][0] = a.x; win[d][1] = a.y; win[d][2] = c.x; win[d][3] = c.y;
            }
            const int cin = cc * 8 + cl;
            #pragma unroll
            for (int g = 0; g < 8; ++g) {
                const float* wg = &wtile[((wvs * 8 + g) * 32 + cin) * 12];
                float4 wa = *(const float4*)wg;
                float4 wb = *(const float4*)(wg + 4);
                float  w8 = wg[8];
                float wt[9] = {wa.x, wa.y, wa.z, wa.w, wb.x, wb.y, wb.z, wb.w, w8};
                #pragma unroll
                for (int d = 0; d < 3; ++d)
                    #pragma unroll
                    for (int j = 0; j < 3; ++j) {
                        float w = wt[3 * d + j];
                        acc[g][0] += w * win[d][j];
                        acc[g][1] += w * win[d][j + 1];
                    }
            }
        }
    }

    // pool: col pair in-lane, row pair via shfl_xor(16); one value per lane/co
    #pragma unroll
    for (int g = 0; g < 8; ++g) {
        float m = fmaxf(LRELU(acc[g][0]), LRELU(acc[g][1]));
        float p = fmaxf(m, __shfl_xor(m, 16));
        if ((R & 1) == 0)
            obuf[((wvs * 8 + g) * 2 + (R >> 1)) * 20 + q + 1] = p;
    }
    __syncthreads();

    // full-line coalesced stores (80 B rows incl. halo cols)
    for (int i = t; i < 320; i += 256) {
        int co_l = i / 10, rem = i % 10, pr = rem / 5, cw = rem % 5;
        *(float4*)&p2H[((b * 64 + cog * 32 + co_l) * 18 + rs * 2 + pr + 1) * 20 + 4 * cw] =
            *(const float4*)&obuf[4 * i];
    }
    if (rs == 0 || rs == 7) {
        int h2 = rs ? 17 : 0;
        for (int i = t; i < 160; i += 256) {
            int co_l = i / 5, cw = i % 5;
            *(float4*)&p2H[((b * 64 + cog * 32 + co_l) * 18 + h2) * 20 + 4 * cw] =
                make_float4(0.f, 0.f, 0.f, 0.f);
        }
    }
}

// ---------- k3: conv3 64->128 @16x16, +b3, lrelu, pool2, mean, dot ---------
// block = 8-co group; waves split cin (16 each); LDS weights + combine.
__global__ __launch_bounds__(256, 2) void k3(const float* __restrict__ p2H,
                                             const float* __restrict__ w3,
                                             const float* __restrict__ b3,
                                             const float* __restrict__ wc,
                                             const float* __restrict__ bc,
                                             float* __restrict__ out) {
    __shared__ __align__(16) float smem[6912];   // wtile [8co][64][12]=6144; cbuf stride36
    const int cog = blockIdx.x;                  // 0..15 -> 8 co
    const int b   = blockIdx.y;
    const int c0  = cog * 8;
    const int t   = threadIdx.x, l = t & 63;
    const int wvs = __builtin_amdgcn_readfirstlane(t >> 6);
    const int r   = l >> 2, q = l & 3;

    for (int i = t; i < 1152; i += 256) {
        float4 v = *(const float4*)&w3[cog * 4608 + 4 * i];
        int e = 4 * i;
        smem[((e + 0) / 9) * 12 + (e + 0) % 9] = v.x;
        smem[((e + 1) / 9) * 12 + (e + 1) % 9] = v.y;
        smem[((e + 2) / 9) * 12 + (e + 2) % 9] = v.z;
        smem[((e + 3) / 9) * 12 + (e + 3) % 9] = v.w;
    }
    __syncthreads();

    float acc[8][4];
    #pragma unroll
    for (int g = 0; g < 8; ++g) {
        float bias = (wvs == 0) ? b3[c0 + g] : 0.f;
        acc[g][0] = bias; acc[g][1] = bias; acc[g][2] = bias; acc[g][3] = bias;
    }

    #pragma unroll 4
    for (int cl = 0; cl < 16; ++cl) {
        const int cin = wvs * 16 + cl;
        const float* pb = p2H + (((b * 64 + cin) * 18 + r) * 20 + 4 * q);
        float win[3][6];
        #pragma unroll
        for (int d = 0; d < 3; ++d) {
            float4 M  = *(const float4*)(pb + d * 20);
            float2 Rt = *(const float2*)(pb + d * 20 + 4);
            win[d][0] = M.x; win[d][1] = M.y; win[d][2] = M.z;
            win[d][3] = M.w; win[d][4] = Rt.x; win[d][5] = Rt.y;
        }
        #pragma unroll
        for (int g = 0; g < 8; ++g) {
            const float* wg = &smem[(g * 64 + cin) * 12];
            float4 wa = *(const float4*)wg;
            float4 wb = *(const float4*)(wg + 4);
            float  w8 = wg[8];
            float wt[9] = {wa.x, wa.y, wa.z, wa.w, wb.x, wb.y, wb.z, wb.w, w8};
            #pragma unroll
            for (int d = 0; d < 3; ++d)
                #pragma unroll
                for (int j = 0; j < 3; ++j) {
                    float w = wt[3 * d + j];
                    acc[g][0] += w * win[d][j];
                    acc[g][1] += w * win[d][j + 1];
                    acc[g][2] += w * win[d][j + 2];
                    acc[g][3] += w * win[d][j + 3];
                }
        }
    }

    __syncthreads();   // weights dead; smem becomes combine buffer (stride 36)
    if (wvs > 0) {
        float* cb = &smem[((wvs - 1) * 64 + l) * 36];
        #pragma unroll
        for (int g = 0; g < 8; ++g)
            *(float4*)&cb[g * 4] =
                make_float4(acc[g][0], acc[g][1], acc[g][2], acc[g][3]);
    }
    __syncthreads();

    if (wvs == 0) {
        #pragma unroll
        for (int k = 0; k < 3; ++k) {
            const float* cb = &smem[(k * 64 + l) * 36];
            #pragma unroll
            for (int g = 0; g < 8; ++g) {
                float4 v = *(const float4*)&cb[g * 4];
                acc[g][0] += v.x; acc[g][1] += v.y;
                acc[g][2] += v.z; acc[g][3] += v.w;
            }
        }
        float vsum = 0.f;
        #pragma unroll
        for (int g = 0; g < 8; ++g) {
            float m0 = fmaxf(LRELU(acc[g][0]), LRELU(acc[g][1]));
            float m1 = fmaxf(LRELU(acc[g][2]), LRELU(acc[g][3]));
            float pm0 = fmaxf(m0, __shfl_xor(m0, 4));   // pool rows r, r+1
            float pm1 = fmaxf(m1, __shfl_xor(m1, 4));
            float contrib = ((r & 1) == 0) ? (pm0 + pm1) : 0.f;
            vsum += contrib * wc[c0 + g];
        }
        #pragma unroll
        for (int off = 32; off > 0; off >>= 1) vsum += __shfl_xor(vsum, off);
        if (l == 0) {
            float o = vsum * (1.f / 64.f);
            if (cog == 0) o += bc[0];
            atomicAdd(&out[b], o);
        }
    }
}

extern "C" void kernel_launch(void* const* d_in, const int* in_sizes, int n_in,
                              void* d_out, int out_size, void* d_ws, size_t ws_size,
                              hipStream_t stream) {
    const float* x  = (const float*)d_in[0];
    const float* w1 = (const float*)d_in[1];
    const float* b1 = (const float*)d_in[2];
    const float* w2 = (const float*)d_in[3];
    const float* b2 = (const float*)d_in[4];
    const float* w3 = (const float*)d_in[5];
    const float* b3 = (const float*)d_in[6];
    const float* wc = (const float*)d_in[7];
    const float* bc = (const float*)d_in[8];
    float* out = (float*)d_out;

    float* P1H = (float*)d_ws;                    // [32][32][34][36] ~5.4 MB
    float* p2H = P1H + P1H_ELEMS;                 // [32][64][18][20] ~2.8 MB

    hipMemsetAsync(out, 0, 32 * sizeof(float), stream);
    k1<<<dim3(32, 32), 256, 0, stream>>>(x, w1, b1, P1H);
    k2<<<dim3(16, 32), 256, 0, stream>>>(P1H, w2, b2, p2H);
    k3<<<dim3(16, 32), 256, 0, stream>>>(p2H, w3, b3, wc, bc, out);
}

// Round 12
// 139.798 us; speedup vs baseline: 1.1865x; 1.0042x over previous
//
#include <hip/hip_runtime.h>

// Problem collapses: output = classifier(node 0) only.
//   out = dot(wc, mean(pool(lrelu(conv3(p2)+b3)))) + bc
//   p2  = pool(lrelu(conv2(12*P1) + 4*b2))   (node 1, indeg=4)
//   P1  = pool(lrelu(conv1(x)+b1))           (sum indegs over {0,2,4,6} = 12)
//
// R12: occupancy + VALU-overhead pass. k2 -> 16 co/block (34 KB LDS, 4
// blocks/CU); k3 -> launch_bounds(256,4) (27.6 KB LDS, 4 blocks/CU); k1
// clamp math hoisted (1 row clamp + col max/min per window row, not per
// load); out-zero folded into k1 (atomics in k3 are stream-ordered after).
// Full-line stores + LDS weight broadcast kept from R11.

#define LRELU(v) fmaxf((v), 0.2f * (v))

#define P1H_ELEMS (32 * 32 * 34 * 36)
#define P2H_ELEMS (32 * 64 * 18 * 20)

// ---------- k1: conv1 4->32 @64x64, +b1, lrelu, pool2, *12 -> P1H ----------
__global__ __launch_bounds__(256, 4) void k1(const float* __restrict__ x,
                                             const float* __restrict__ w1,
                                             const float* __restrict__ b1,
                                             float* __restrict__ P1H,
                                             float* __restrict__ out) {
    __shared__ __align__(16) float obuf[1152];     // [4co][8prow][36]
    const int bx = blockIdx.x;                     // 32 = rb(4) x cog(8)
    const int b  = blockIdx.y;
    const int rb = bx & 3, cog = bx >> 2;
    const int t  = threadIdx.x;
    const int l  = t & 63, wv = t >> 6;
    const int r  = l >> 4, q = l & 15;
    const int row0 = 16 * rb + 4 * wv + r;         // pre-pool row 0..63

    if (bx == 0 && t == 0) out[b] = 0.f;           // k3 atomics ordered after

    for (int i = t; i < 288; i += 256)
        *(float4*)&obuf[4 * i] = make_float4(0.f, 0.f, 0.f, 0.f);
    __syncthreads();

    const bool cL = (q > 0), cR = (q < 15);
    const int colL = max(4 * q - 2, 0);            // float2 covers 4q-2,4q-1
    const int colR = min(4 * q + 4, 62);           // float2 covers 4q+4,4q+5

    float acc[4][4];
    #pragma unroll
    for (int g = 0; g < 4; ++g) {
        float bias = b1[cog * 4 + g];
        acc[g][0] = bias; acc[g][1] = bias; acc[g][2] = bias; acc[g][3] = bias;
    }

    #pragma unroll
    for (int c = 0; c < 4; ++c) {
        float win[3][6];
        #pragma unroll
        for (int d = 0; d < 3; ++d) {
            int gr = row0 - 1 + d;
            bool v = (unsigned)gr < 64u;
            int grc = min(max(gr, 0), 63);
            const float* row = x + ((b * 4 + c) * 64 + grc) * 64;
            float2 L  = *(const float2*)(row + colL);
            float4 M  = *(const float4*)(row + 4 * q);
            float2 R2 = *(const float2*)(row + colR);
            win[d][0] = (v && cL) ? L.y : 0.f;
            win[d][1] = v ? M.x : 0.f;
            win[d][2] = v ? M.y : 0.f;
            win[d][3] = v ? M.z : 0.f;
            win[d][4] = v ? M.w : 0.f;
            win[d][5] = (v && cR) ? R2.x : 0.f;
        }
        #pragma unroll
        for (int g = 0; g < 4; ++g) {
            const float* wp = &w1[((cog * 4 + g) * 4 + c) * 9];  // tiny K$ set
            #pragma unroll
            for (int d = 0; d < 3; ++d)
                #pragma unroll
                for (int j = 0; j < 3; ++j) {
                    float w = wp[3 * d + j];
                    acc[g][0] += w * win[d][j];
                    acc[g][1] += w * win[d][j + 1];
                    acc[g][2] += w * win[d][j + 2];
                    acc[g][3] += w * win[d][j + 3];
                }
        }
    }

    const int prow_l = 2 * wv + (r >> 1);
    #pragma unroll
    for (int g = 0; g < 4; ++g) {
        float m0 = fmaxf(LRELU(acc[g][0]), LRELU(acc[g][1]));
        float m1 = fmaxf(LRELU(acc[g][2]), LRELU(acc[g][3]));
        float p0 = fmaxf(m0, __shfl_xor(m0, 16));   // all lanes execute
        float p1 = fmaxf(m1, __shfl_xor(m1, 16));
        if ((r & 1) == 0) {
            obuf[(g * 8 + prow_l) * 36 + 2 * q + 1] = 12.f * p0;
            obuf[(g * 8 + prow_l) * 36 + 2 * q + 2] = 12.f * p1;
        }
    }
    __syncthreads();

    // full-line coalesced stores (rows incl. halo cols)
    for (int i = t; i < 288; i += 256) {
        int co_l = i / 72, rem = i % 72, pr = rem / 9, cw = rem % 9;
        *(float4*)&P1H[((b * 32 + cog * 4 + co_l) * 34 + 8 * rb + pr + 1) * 36 + 4 * cw] =
            *(const float4*)&obuf[4 * i];
    }
    if (rb == 0 || rb == 3) {
        int h = rb ? 33 : 0;
        for (int i = t; i < 36; i += 256) {
            int co_l = i / 9, cw = i % 9;
            *(float4*)&P1H[((b * 32 + cog * 4 + co_l) * 34 + h) * 36 + 4 * cw] =
                make_float4(0.f, 0.f, 0.f, 0.f);
        }
    }
}

// ---------- k2: conv2 32->64 @32x32, +4*b2, lrelu, pool2 -> p2H ------------
// 16 co/block (4 waves x 4 co); block = 4-row strip; 34 KB LDS -> 4 blk/CU.
__global__ __launch_bounds__(256, 4) void k2(const float* __restrict__ P1H,
                                             const float* __restrict__ w2,
                                             const float* __restrict__ b2,
                                             float* __restrict__ p2H) {
    __shared__ __align__(16) float wtile[6144];    // [16co][32cin][12] 24.6 KB
    __shared__ __align__(16) float xin[1728];      // [8cin][6row][36]   6.9 KB
    __shared__ __align__(16) float obuf[640];      // [16co][2prow][20]  2.6 KB
    const int bx = blockIdx.x;                     // 32 = cog(4) x rs(8)
    const int b  = blockIdx.y;
    const int cog = bx >> 3, rs = bx & 7;
    const int c0  = cog * 16;
    const int t  = threadIdx.x, l = t & 63;
    const int wvs = __builtin_amdgcn_readfirstlane(t >> 6);
    const int q  = l & 15, R = l >> 4;             // cols 2q,2q+1; row rs*4+R

    // stage weights: contiguous float4 reads, scatter to stride-12 (pad 9->12)
    for (int i = t; i < 1152; i += 256) {
        float4 v = *(const float4*)&w2[cog * 4608 + 4 * i];
        int e = 4 * i;
        wtile[((e + 0) / 9) * 12 + (e + 0) % 9] = v.x;
        wtile[((e + 1) / 9) * 12 + (e + 1) % 9] = v.y;
        wtile[((e + 2) / 9) * 12 + (e + 2) % 9] = v.z;
        wtile[((e + 3) / 9) * 12 + (e + 3) % 9] = v.w;
    }
    for (int i = t; i < 160; i += 256)
        *(float4*)&obuf[4 * i] = make_float4(0.f, 0.f, 0.f, 0.f);

    float acc[4][2];
    #pragma unroll
    for (int g = 0; g < 4; ++g) {
        float bias = 4.f * b2[c0 + wvs * 4 + g];
        acc[g][0] = bias; acc[g][1] = bias;
    }

    for (int cc = 0; cc < 4; ++cc) {
        __syncthreads();
        for (int i = t; i < 432; i += 256) {       // 8 cin x 6 rows x 9 f4
            int cin_l = i / 54, rem = i % 54;
            *(float4*)&xin[cin_l * 216 + 4 * rem] =
                *(const float4*)&P1H[((b * 32 + cc * 8 + cin_l) * 34 + rs * 4) * 36 + 4 * rem];
        }
        __syncthreads();
        #pragma unroll
        for (int cl = 0; cl < 8; ++cl) {
            float win[3][4];
            #pragma unroll
            for (int d = 0; d < 3; ++d) {
                const float* xr = &xin[cl * 216 + (R + d) * 36 + 2 * q];
                float2 a = *(const float2*)xr;
                float2 c = *(const float2*)(xr + 2);
                win[d][0] = a.x; win[d][1] = a.y; win[d][2] = c.x; win[d][3] = c.y;
            }
            const int cin = cc * 8 + cl;
            #pragma unroll
            for (int g = 0; g < 4; ++g) {
                const float* wg = &wtile[((wvs * 4 + g) * 32 + cin) * 12];
                float4 wa = *(const float4*)wg;
                float4 wb = *(const float4*)(wg + 4);
                float  w8 = wg[8];
                float wt[9] = {wa.x, wa.y, wa.z, wa.w, wb.x, wb.y, wb.z, wb.w, w8};
                #pragma unroll
                for (int d = 0; d < 3; ++d)
                    #pragma unroll
                    for (int j = 0; j < 3; ++j) {
                        float w = wt[3 * d + j];
                        acc[g][0] += w * win[d][j];
                        acc[g][1] += w * win[d][j + 1];
                    }
            }
        }
    }

    // pool: col pair in-lane, row pair via shfl_xor(16)
    #pragma unroll
    for (int g = 0; g < 4; ++g) {
        float m = fmaxf(LRELU(acc[g][0]), LRELU(acc[g][1]));
        float p = fmaxf(m, __shfl_xor(m, 16));
        if ((R & 1) == 0)
            obuf[((wvs * 4 + g) * 2 + (R >> 1)) * 20 + q + 1] = p;
    }
    __syncthreads();

    // full-line coalesced stores (80 B rows incl. halo cols)
    for (int i = t; i < 160; i += 256) {
        int co_l = i / 10, rem = i % 10, pr = rem / 5, cw = rem % 5;
        *(float4*)&p2H[((b * 64 + c0 + co_l) * 18 + rs * 2 + pr + 1) * 20 + 4 * cw] =
            *(const float4*)&obuf[4 * i];
    }
    if (rs == 0 || rs == 7) {
        int h2 = rs ? 17 : 0;
        for (int i = t; i < 80; i += 256) {
            int co_l = i / 5, cw = i % 5;
            *(float4*)&p2H[((b * 64 + c0 + co_l) * 18 + h2) * 20 + 4 * cw] =
                make_float4(0.f, 0.f, 0.f, 0.f);
        }
    }
}

// ---------- k3: conv3 64->128 @16x16, +b3, lrelu, pool2, mean, dot ---------
// block = 8-co group; waves split cin (16 each); 27.6 KB LDS -> 4 blk/CU.
__global__ __launch_bounds__(256, 4) void k3(const float* __restrict__ p2H,
                                             const float* __restrict__ w3,
                                             const float* __restrict__ b3,
                                             const float* __restrict__ wc,
                                             const float* __restrict__ bc,
                                             float* __restrict__ out) {
    __shared__ __align__(16) float smem[6912];   // wtile [8co][64][12]=6144; cbuf stride36
    const int cog = blockIdx.x;                  // 0..15 -> 8 co
    const int b   = blockIdx.y;
    const int c0  = cog * 8;
    const int t   = threadIdx.x, l = t & 63;
    const int wvs = __builtin_amdgcn_readfirstlane(t >> 6);
    const int r   = l >> 2, q = l & 3;

    for (int i = t; i < 1152; i += 256) {
        float4 v = *(const float4*)&w3[cog * 4608 + 4 * i];
        int e = 4 * i;
        smem[((e + 0) / 9) * 12 + (e + 0) % 9] = v.x;
        smem[((e + 1) / 9) * 12 + (e + 1) % 9] = v.y;
        smem[((e + 2) / 9) * 12 + (e + 2) % 9] = v.z;
        smem[((e + 3) / 9) * 12 + (e + 3) % 9] = v.w;
    }
    __syncthreads();

    float acc[8][4];
    #pragma unroll
    for (int g = 0; g < 8; ++g) {
        float bias = (wvs == 0) ? b3[c0 + g] : 0.f;
        acc[g][0] = bias; acc[g][1] = bias; acc[g][2] = bias; acc[g][3] = bias;
    }

    #pragma unroll 4
    for (int cl = 0; cl < 16; ++cl) {
        const int cin = wvs * 16 + cl;
        const float* pb = p2H + (((b * 64 + cin) * 18 + r) * 20 + 4 * q);
        float win[3][6];
        #pragma unroll
        for (int d = 0; d < 3; ++d) {
            float4 M  = *(const float4*)(pb + d * 20);
            float2 Rt = *(const float2*)(pb + d * 20 + 4);
            win[d][0] = M.x; win[d][1] = M.y; win[d][2] = M.z;
            win[d][3] = M.w; win[d][4] = Rt.x; win[d][5] = Rt.y;
        }
        #pragma unroll
        for (int g = 0; g < 8; ++g) {
            const float* wg = &smem[(g * 64 + cin) * 12];
            float4 wa = *(const float4*)wg;
            float4 wb = *(const float4*)(wg + 4);
            float  w8 = wg[8];
            float wt[9] = {wa.x, wa.y, wa.z, wa.w, wb.x, wb.y, wb.z, wb.w, w8};
            #pragma unroll
            for (int d = 0; d < 3; ++d)
                #pragma unroll
                for (int j = 0; j < 3; ++j) {
                    float w = wt[3 * d + j];
                    acc[g][0] += w * win[d][j];
                    acc[g][1] += w * win[d][j + 1];
                    acc[g][2] += w * win[d][j + 2];
                    acc[g][3] += w * win[d][j + 3];
                }
        }
    }

    __syncthreads();   // weights dead; smem becomes combine buffer (stride 36)
    if (wvs > 0) {
        float* cb = &smem[((wvs - 1) * 64 + l) * 36];
        #pragma unroll
        for (int g = 0; g < 8; ++g)
            *(float4*)&cb[g * 4] =
                make_float4(acc[g][0], acc[g][1], acc[g][2], acc[g][3]);
    }
    __syncthreads();

    if (wvs == 0) {
        #pragma unroll
        for (int k = 0; k < 3; ++k) {
            const float* cb = &smem[(k * 64 + l) * 36];
            #pragma unroll
            for (int g = 0; g < 8; ++g) {
                float4 v = *(const float4*)&cb[g * 4];
                acc[g][0] += v.x; acc[g][1] += v.y;
                acc[g][2] += v.z; acc[g][3] += v.w;
            }
        }
        float vsum = 0.f;
        #pragma unroll
        for (int g = 0; g < 8; ++g) {
            float m0 = fmaxf(LRELU(acc[g][0]), LRELU(acc[g][1]));
            float m1 = fmaxf(LRELU(acc[g][2]), LRELU(acc[g][3]));
            float pm0 = fmaxf(m0, __shfl_xor(m0, 4));   // pool rows r, r+1
            float pm1 = fmaxf(m1, __shfl_xor(m1, 4));
            float contrib = ((r & 1) == 0) ? (pm0 + pm1) : 0.f;
            vsum += contrib * wc[c0 + g];
        }
        #pragma unroll
        for (int off = 32; off > 0; off >>= 1) vsum += __shfl_xor(vsum, off);
        if (l == 0) {
            float o = vsum * (1.f / 64.f);
            if (cog == 0) o += bc[0];
            atomicAdd(&out[b], o);
        }
    }
}

extern "C" void kernel_launch(void* const* d_in, const int* in_sizes, int n_in,
                              void* d_out, int out_size, void* d_ws, size_t ws_size,
                              hipStream_t stream) {
    const float* x  = (const float*)d_in[0];
    const float* w1 = (const float*)d_in[1];
    const float* b1 = (const float*)d_in[2];
    const float* w2 = (const float*)d_in[3];
    const float* b2 = (const float*)d_in[4];
    const float* w3 = (const float*)d_in[5];
    const float* b3 = (const float*)d_in[6];
    const float* wc = (const float*)d_in[7];
    const float* bc = (const float*)d_in[8];
    float* out = (float*)d_out;

    float* P1H = (float*)d_ws;                    // [32][32][34][36] ~5.4 MB
    float* p2H = P1H + P1H_ELEMS;                 // [32][64][18][20] ~2.8 MB

    k1<<<dim3(32, 32), 256, 0, stream>>>(x, w1, b1, P1H, out);
    k2<<<dim3(32, 32), 256, 0, stream>>>(P1H, w2, b2, p2H);
    k3<<<dim3(16, 32), 256, 0, stream>>>(p2H, w3, b3, wc, bc, out);
}

// Round 13
// 136.324 us; speedup vs baseline: 1.2167x; 1.0255x over previous
//
#include <hip/hip_runtime.h>

// Problem collapses: output = classifier(node 0) only.
//   out = dot(wc, mean(pool(lrelu(conv3(p2)+b3)))) + bc
//   p2  = pool(lrelu(conv2(12*P1) + 4*b2))   (node 1, indeg=4)
//   P1  = pool(lrelu(conv1(x)+b1))           (sum indegs over {0,2,4,6} = 12)
//
// R13: FMA:LDS ratio + grid fix. k2 lanes own 4 output cols (288 VALU-cyc
// vs ~170 LDS-cyc per cl -> VALU-bound), waves split co (full cin sum, no
// combine). k3 back to 32cogx4co = 1024 blocks (4/CU). Full-line stores,
// LDS weight broadcast, haloed layouts kept.

#define LRELU(v) fmaxf((v), 0.2f * (v))

#define P1H_ELEMS (32 * 32 * 34 * 36)
#define P2H_ELEMS (32 * 64 * 18 * 20)

// ---------- k1: conv1 4->32 @64x64, +b1, lrelu, pool2, *12 -> P1H ----------
__global__ __launch_bounds__(256, 4) void k1(const float* __restrict__ x,
                                             const float* __restrict__ w1,
                                             const float* __restrict__ b1,
                                             float* __restrict__ P1H,
                                             float* __restrict__ out) {
    __shared__ __align__(16) float obuf[1152];     // [4co][8prow][36]
    const int bx = blockIdx.x;                     // 32 = rb(4) x cog(8)
    const int b  = blockIdx.y;
    const int rb = bx & 3, cog = bx >> 2;
    const int t  = threadIdx.x;
    const int l  = t & 63, wv = t >> 6;
    const int r  = l >> 4, q = l & 15;
    const int row0 = 16 * rb + 4 * wv + r;         // pre-pool row 0..63

    if (bx == 0 && t == 0) out[b] = 0.f;           // k3 atomics ordered after

    for (int i = t; i < 288; i += 256)
        *(float4*)&obuf[4 * i] = make_float4(0.f, 0.f, 0.f, 0.f);
    __syncthreads();

    const bool cL = (q > 0), cR = (q < 15);
    const int colL = max(4 * q - 2, 0);
    const int colR = min(4 * q + 4, 62);

    float acc[4][4];
    #pragma unroll
    for (int g = 0; g < 4; ++g) {
        float bias = b1[cog * 4 + g];
        acc[g][0] = bias; acc[g][1] = bias; acc[g][2] = bias; acc[g][3] = bias;
    }

    #pragma unroll
    for (int c = 0; c < 4; ++c) {
        float win[3][6];
        #pragma unroll
        for (int d = 0; d < 3; ++d) {
            int gr = row0 - 1 + d;
            bool v = (unsigned)gr < 64u;
            int grc = min(max(gr, 0), 63);
            const float* row = x + ((b * 4 + c) * 64 + grc) * 64;
            float2 L  = *(const float2*)(row + colL);
            float4 M  = *(const float4*)(row + 4 * q);
            float2 R2 = *(const float2*)(row + colR);
            win[d][0] = (v && cL) ? L.y : 0.f;
            win[d][1] = v ? M.x : 0.f;
            win[d][2] = v ? M.y : 0.f;
            win[d][3] = v ? M.z : 0.f;
            win[d][4] = v ? M.w : 0.f;
            win[d][5] = (v && cR) ? R2.x : 0.f;
        }
        #pragma unroll
        for (int g = 0; g < 4; ++g) {
            const float* wp = &w1[((cog * 4 + g) * 4 + c) * 9];  // tiny K$ set
            #pragma unroll
            for (int d = 0; d < 3; ++d)
                #pragma unroll
                for (int j = 0; j < 3; ++j) {
                    float w = wp[3 * d + j];
                    acc[g][0] += w * win[d][j];
                    acc[g][1] += w * win[d][j + 1];
                    acc[g][2] += w * win[d][j + 2];
                    acc[g][3] += w * win[d][j + 3];
                }
        }
    }

    const int prow_l = 2 * wv + (r >> 1);
    #pragma unroll
    for (int g = 0; g < 4; ++g) {
        float m0 = fmaxf(LRELU(acc[g][0]), LRELU(acc[g][1]));
        float m1 = fmaxf(LRELU(acc[g][2]), LRELU(acc[g][3]));
        float p0 = fmaxf(m0, __shfl_xor(m0, 16));
        float p1 = fmaxf(m1, __shfl_xor(m1, 16));
        if ((r & 1) == 0) {
            obuf[(g * 8 + prow_l) * 36 + 2 * q + 1] = 12.f * p0;
            obuf[(g * 8 + prow_l) * 36 + 2 * q + 2] = 12.f * p1;
        }
    }
    __syncthreads();

    for (int i = t; i < 288; i += 256) {
        int co_l = i / 72, rem = i % 72, pr = rem / 9, cw = rem % 9;
        *(float4*)&P1H[((b * 32 + cog * 4 + co_l) * 34 + 8 * rb + pr + 1) * 36 + 4 * cw] =
            *(const float4*)&obuf[4 * i];
    }
    if (rb == 0 || rb == 3) {
        int h = rb ? 33 : 0;
        for (int i = t; i < 36; i += 256) {
            int co_l = i / 9, cw = i % 9;
            *(float4*)&P1H[((b * 32 + cog * 4 + co_l) * 34 + h) * 36 + 4 * cw] =
                make_float4(0.f, 0.f, 0.f, 0.f);
        }
    }
}

// ---------- k2: conv2 32->64 @32x32, +4*b2, lrelu, pool2 -> p2H ------------
// block = (cog 4 x 16co) x (rs 4 x 8rows); waves split CO (4 each, full cin
// sum, no combine). Lanes own 4 cols x 1 row.
__global__ __launch_bounds__(256, 2) void k2(const float* __restrict__ P1H,
                                             const float* __restrict__ w2,
                                             const float* __restrict__ b2,
                                             float* __restrict__ p2H) {
    __shared__ __align__(16) float wtile[6144];    // [16co][32cin][12] 24.6 KB
    __shared__ __align__(16) float xin[2880];      // [8cin][10row][36] 11.5 KB
    __shared__ __align__(16) float obuf[1280];     // [16co][4prow][20]  5.1 KB
    const int bx = blockIdx.x;                     // 16 = cog(4) x rs(4)
    const int b  = blockIdx.y;
    const int cog = bx >> 2, rs = bx & 3;
    const int c0  = cog * 16;
    const int t  = threadIdx.x, l = t & 63;
    const int wvs = __builtin_amdgcn_readfirstlane(t >> 6);
    const int q  = l & 7, R = l >> 3;              // cols 4q..4q+3; row rs*8+R

    // stage weights: contiguous float4 reads, scatter to stride-12 (pad 9->12)
    for (int i = t; i < 1152; i += 256) {
        float4 v = *(const float4*)&w2[cog * 4608 + 4 * i];
        int e = 4 * i;
        wtile[((e + 0) / 9) * 12 + (e + 0) % 9] = v.x;
        wtile[((e + 1) / 9) * 12 + (e + 1) % 9] = v.y;
        wtile[((e + 2) / 9) * 12 + (e + 2) % 9] = v.z;
        wtile[((e + 3) / 9) * 12 + (e + 3) % 9] = v.w;
    }
    for (int i = t; i < 320; i += 256)
        *(float4*)&obuf[4 * i] = make_float4(0.f, 0.f, 0.f, 0.f);

    float acc[4][4];
    #pragma unroll
    for (int g = 0; g < 4; ++g) {
        float bias = 4.f * b2[c0 + wvs * 4 + g];   // wave owns these co fully
        acc[g][0] = bias; acc[g][1] = bias; acc[g][2] = bias; acc[g][3] = bias;
    }

    for (int cc = 0; cc < 4; ++cc) {
        __syncthreads();
        for (int i = t; i < 720; i += 256) {       // 8 cin x 10 rows x 9 f4
            int cin_l = i / 90, rem = i % 90;
            *(float4*)&xin[cin_l * 360 + 4 * rem] =
                *(const float4*)&P1H[((b * 32 + cc * 8 + cin_l) * 34 + rs * 8) * 36 + 4 * rem];
        }
        __syncthreads();
        #pragma unroll
        for (int cl = 0; cl < 8; ++cl) {
            float win[3][6];
            #pragma unroll
            for (int d = 0; d < 3; ++d) {
                const float* xr = &xin[cl * 360 + (R + d) * 36 + 4 * q];
                float4 M  = *(const float4*)xr;
                float2 Rt = *(const float2*)(xr + 4);
                win[d][0] = M.x; win[d][1] = M.y; win[d][2] = M.z;
                win[d][3] = M.w; win[d][4] = Rt.x; win[d][5] = Rt.y;
            }
            const int cin = cc * 8 + cl;
            #pragma unroll
            for (int g = 0; g < 4; ++g) {
                const float* wg = &wtile[((wvs * 4 + g) * 32 + cin) * 12];
                float4 wa = *(const float4*)wg;
                float4 wb = *(const float4*)(wg + 4);
                float  w8 = wg[8];
                float wt[9] = {wa.x, wa.y, wa.z, wa.w, wb.x, wb.y, wb.z, wb.w, w8};
                #pragma unroll
                for (int d = 0; d < 3; ++d)
                    #pragma unroll
                    for (int j = 0; j < 3; ++j) {
                        float w = wt[3 * d + j];
                        acc[g][0] += w * win[d][j];
                        acc[g][1] += w * win[d][j + 1];
                        acc[g][2] += w * win[d][j + 2];
                        acc[g][3] += w * win[d][j + 3];
                    }
            }
        }
    }

    // pool: col pairs in-lane; row pair via shfl_xor(8) (R <-> R^1)
    #pragma unroll
    for (int g = 0; g < 4; ++g) {
        float m0 = fmaxf(LRELU(acc[g][0]), LRELU(acc[g][1]));
        float m1 = fmaxf(LRELU(acc[g][2]), LRELU(acc[g][3]));
        float p0 = fmaxf(m0, __shfl_xor(m0, 8));
        float p1 = fmaxf(m1, __shfl_xor(m1, 8));
        if ((R & 1) == 0) {
            int co_l = wvs * 4 + g;
            obuf[(co_l * 4 + (R >> 1)) * 20 + 2 * q + 1] = p0;
            obuf[(co_l * 4 + (R >> 1)) * 20 + 2 * q + 2] = p1;
        }
    }
    __syncthreads();

    // full-line coalesced stores (80 B rows incl. halo cols)
    for (int i = t; i < 320; i += 256) {
        int co_l = i / 20, rem = i % 20, pr = rem / 5, cw = rem % 5;
        *(float4*)&p2H[((b * 64 + c0 + co_l) * 18 + rs * 4 + pr + 1) * 20 + 4 * cw] =
            *(const float4*)&obuf[4 * i];
    }
    if (rs == 0 || rs == 3) {
        int h2 = rs ? 17 : 0;
        for (int i = t; i < 80; i += 256) {
            int co_l = i / 5, cw = i % 5;
            *(float4*)&p2H[((b * 64 + c0 + co_l) * 18 + h2) * 20 + 4 * cw] =
                make_float4(0.f, 0.f, 0.f, 0.f);
        }
    }
}

// ---------- k3: conv3 64->128 @16x16, +b3, lrelu, pool2, mean, dot ---------
// block = 4-co group (32 of them, 1024 blocks = 4/CU); waves split cin.
__global__ __launch_bounds__(256, 4) void k3(const float* __restrict__ p2H,
                                             const float* __restrict__ w3,
                                             const float* __restrict__ b3,
                                             const float* __restrict__ wc,
                                             const float* __restrict__ bc,
                                             float* __restrict__ out) {
    __shared__ __align__(16) float smem[3072];   // wtile [4co][64][12]; cbuf stride16
    const int cog = blockIdx.x;                  // 0..31 -> 4 co
    const int b   = blockIdx.y;
    const int c0  = cog * 4;
    const int t   = threadIdx.x, l = t & 63;
    const int wvs = __builtin_amdgcn_readfirstlane(t >> 6);
    const int r   = l >> 2, q = l & 3;

    for (int i = t; i < 576; i += 256) {         // 4co x 64cin x 9 = 2304 = 576 f4
        float4 v = *(const float4*)&w3[cog * 2304 + 4 * i];
        int e = 4 * i;
        smem[((e + 0) / 9) * 12 + (e + 0) % 9] = v.x;
        smem[((e + 1) / 9) * 12 + (e + 1) % 9] = v.y;
        smem[((e + 2) / 9) * 12 + (e + 2) % 9] = v.z;
        smem[((e + 3) / 9) * 12 + (e + 3) % 9] = v.w;
    }
    __syncthreads();

    float acc[4][4];
    #pragma unroll
    for (int g = 0; g < 4; ++g) {
        float bias = (wvs == 0) ? b3[c0 + g] : 0.f;
        acc[g][0] = bias; acc[g][1] = bias; acc[g][2] = bias; acc[g][3] = bias;
    }

    #pragma unroll
    for (int cl = 0; cl < 16; ++cl) {
        const int cin = wvs * 16 + cl;
        const float* pb = p2H + (((b * 64 + cin) * 18 + r) * 20 + 4 * q);
        float win[3][6];
        #pragma unroll
        for (int d = 0; d < 3; ++d) {
            float4 M  = *(const float4*)(pb + d * 20);
            float2 Rt = *(const float2*)(pb + d * 20 + 4);
            win[d][0] = M.x; win[d][1] = M.y; win[d][2] = M.z;
            win[d][3] = M.w; win[d][4] = Rt.x; win[d][5] = Rt.y;
        }
        #pragma unroll
        for (int g = 0; g < 4; ++g) {
            const float* wg = &smem[(g * 64 + cin) * 12];
            float4 wa = *(const float4*)wg;
            float4 wb = *(const float4*)(wg + 4);
            float  w8 = wg[8];
            float wt[9] = {wa.x, wa.y, wa.z, wa.w, wb.x, wb.y, wb.z, wb.w, w8};
            #pragma unroll
            for (int d = 0; d < 3; ++d)
                #pragma unroll
                for (int j = 0; j < 3; ++j) {
                    float w = wt[3 * d + j];
                    acc[g][0] += w * win[d][j];
                    acc[g][1] += w * win[d][j + 1];
                    acc[g][2] += w * win[d][j + 2];
                    acc[g][3] += w * win[d][j + 3];
                }
        }
    }

    __syncthreads();   // weights dead; smem becomes combine buffer (stride 16)
    if (wvs > 0) {
        float* cb = &smem[((wvs - 1) * 64 + l) * 16];
        #pragma unroll
        for (int g = 0; g < 4; ++g)
            *(float4*)&cb[g * 4] =
                make_float4(acc[g][0], acc[g][1], acc[g][2], acc[g][3]);
    }
    __syncthreads();

    if (wvs == 0) {
        #pragma unroll
        for (int k = 0; k < 3; ++k) {
            const float* cb = &smem[(k * 64 + l) * 16];
            #pragma unroll
            for (int g = 0; g < 4; ++g) {
                float4 v = *(const float4*)&cb[g * 4];
                acc[g][0] += v.x; acc[g][1] += v.y;
                acc[g][2] += v.z; acc[g][3] += v.w;
            }
        }
        float vsum = 0.f;
        #pragma unroll
        for (int g = 0; g < 4; ++g) {
            float m0 = fmaxf(LRELU(acc[g][0]), LRELU(acc[g][1]));
            float m1 = fmaxf(LRELU(acc[g][2]), LRELU(acc[g][3]));
            float pm0 = fmaxf(m0, __shfl_xor(m0, 4));
            float pm1 = fmaxf(m1, __shfl_xor(m1, 4));
            float contrib = ((r & 1) == 0) ? (pm0 + pm1) : 0.f;
            vsum += contrib * wc[c0 + g];
        }
        #pragma unroll
        for (int off = 32; off > 0; off >>= 1) vsum += __shfl_xor(vsum, off);
        if (l == 0) {
            float o = vsum * (1.f / 64.f);
            if (cog == 0) o += bc[0];
            atomicAdd(&out[b], o);
        }
    }
}

extern "C" void kernel_launch(void* const* d_in, const int* in_sizes, int n_in,
                              void* d_out, int out_size, void* d_ws, size_t ws_size,
                              hipStream_t stream) {
    const float* x  = (const float*)d_in[0];
    const float* w1 = (const float*)d_in[1];
    const float* b1 = (const float*)d_in[2];
    const float* w2 = (const float*)d_in[3];
    const float* b2 = (const float*)d_in[4];
    const float* w3 = (const float*)d_in[5];
    const float* b3 = (const float*)d_in[6];
    const float* wc = (const float*)d_in[7];
    const float* bc = (const float*)d_in[8];
    float* out = (float*)d_out;

    float* P1H = (float*)d_ws;                    // [32][32][34][36] ~5.4 MB
    float* p2H = P1H + P1H_ELEMS;                 // [32][64][18][20] ~2.8 MB

    k1<<<dim3(32, 32), 256, 0, stream>>>(x, w1, b1, P1H, out);
    k2<<<dim3(16, 32), 256, 0, stream>>>(P1H, w2, b2, p2H);
    k3<<<dim3(32, 32), 256, 0, stream>>>(p2H, w3, b3, wc, bc, out);
}